// Round 9
// baseline (280.522 us; speedup 1.0000x reference)
//
#include <hip/hip_runtime.h>

// SNN forward, 2 launches: [prep: X transpose + W splits + flag zero] ->
// [MEGA: gemm1+scan1 (R6-proven, ballot bit spikes) -> self-sync flags ->
//  gemm2 (R6-proven bit-A + wave-private LDS B, no barriers) -> flags ->
//  scan2 (direct Out)].  One kernel replaces three: kills 2 launch-DAG
// edges + tails. Cross-block sync: device-scope release/acquire atomics
// (guide G16); deadlock-free (every block produces before any spin; all
// 512 blocks co-resident at 2/CU).
// f16 split-2: W = hi + lo (both f16), residual ~2^-24 => fp32-grade MFMA.
// R9 ledger: gemm1 66.5 invariant {dbuf, ring3+swz, interleave, bit-A(83!)}
// => phase-lockstep wait, interior fixes exhausted. rest ~120-122 invariant
// across 4 gemm2 structures => probe the launch DAG itself.

#define NN 64
#define II 256
#define HH 1024
#define OO 18
#define TT 500

#define D_SR 0.9048374180359595f   // exp(-1/10)
#define C_SR 0.27182818284590454f  // e/10
#define D_RF 0.36787944117144233f  // exp(-1)
#define C_RF 2.718281828459045f    // e
#define THETA 10.0f
#define REFS (-20.0f)

typedef _Float16 f16;
typedef _Float16 f16x8 __attribute__((ext_vector_type(8)));
typedef float f32x4 __attribute__((ext_vector_type(4)));
typedef unsigned int uint;
typedef unsigned long long u64;

__device__ __forceinline__ void gl2lds16(const void* g, void* l) {
    __builtin_amdgcn_global_load_lds(
        (const __attribute__((address_space(1))) void*)g,
        (__attribute__((address_space(3))) void*)l, 16, 0, 0);
}

// ---------------- prep: X transpose + W1 hi/lo + W2 hi/lo + flag zero ------
// grid 3200: [0,2048) X tiles, [2048,3072) W1, [3072,3200) W2 (+flags @3072).
__launch_bounds__(256)
__global__ void prep_all(const float* __restrict__ X, const float* __restrict__ W1,
                         const float* __restrict__ W2, f16* __restrict__ Xb,
                         f16* __restrict__ W1h, f16* __restrict__ W1l,
                         f16* __restrict__ W2h, f16* __restrict__ W2l,
                         uint* __restrict__ flags) {
    __shared__ float tile[64][65];
    const int b = blockIdx.x;
    const int tid = threadIdx.x;

    if (b < 2048) {
        const int t0 = (b & 7) * 64, i0 = ((b >> 3) & 3) * 64, n = b >> 5;
        const int tx = tid & 63, q = tid >> 6;
        const float* Xn = X + (size_t)n * II * TT;
#pragma unroll 4
        for (int j = 0; j < 16; ++j) {
            int il = j * 4 + q;
            int t = t0 + tx;
            tile[il][tx] = (t < TT) ? Xn[(size_t)(i0 + il) * TT + t] : 0.f;
        }
        __syncthreads();
#pragma unroll 4
        for (int j = 0; j < 16; ++j) {
            int tl = j * 4 + q;
            int t = t0 + tl;
            if (t < TT)
                Xb[((size_t)n * TT + t) * II + i0 + tx] = (f16)tile[tx][tl];
        }
    } else if (b < 3072) {
        int idx = (b - 2048) * 256 + tid;
        float w = W1[idx];
        f16 h = (f16)w;
        f16 l = (f16)(w - (float)h);
        W1h[idx] = h;
        W1l[idx] = l;
    } else {
        if (b == 3072 && tid < 128) flags[tid] = 0;   // done[64] + y2done[64]
        int idx = (b - 3072) * 256 + tid;
        int o = idx >> 10;
        float w = (o < OO) ? W2[idx] : 0.f;
        f16 h = (f16)w;
        f16 l = (f16)(w - (float)h);
        W2h[idx] = h;
        W2l[idx] = l;
    }
}

// ---------------- MEGA: gemm1+scan1 -> gemm2 -> scan2, self-synced ----------
// grid 512 x 512 thr (exactly 2 blocks/CU, all co-resident).
__launch_bounds__(512, 4)
__global__ void mega(const f16* __restrict__ Xb, const f16* __restrict__ Wh,
                     const f16* __restrict__ Wl, u64* __restrict__ Sb,
                     const f16* __restrict__ W2h, const f16* __restrict__ W2l,
                     float* __restrict__ Y2, float* __restrict__ Out,
                     uint* __restrict__ flags) {
    __shared__ __align__(16) char smem[3 * 24576];  // 73,728 B, reused per phase

    const int b = blockIdx.x;
    const int tid = threadIdx.x;
    const int wave = tid >> 6, lane = tid & 63;
    uint* done = flags;
    uint* y2f  = flags + 64;

    // ================= PHASE A: gemm1 + scan1 (R6-proven body) =============
    {
        float* yb = (float*)smem;
        // XCD swizzle (f = b reproduces the old dim3(8,NN) mapping)
        const int x = b & 7, g = b >> 3;
        const int nA = x * 8 + (g & 7);
        const int ht = g >> 3;
        const int h0g = ht * 128;

        const int rbl = wave * 16 + (lane >> 2);
        const int koff = (((lane & 3) ^ ((lane >> 3) & 3))) * 8;
        const f16* gBh0 = Wh + (size_t)(h0g + rbl) * II + koff;
        const f16* gBl0 = Wl + (size_t)(h0g + rbl) * II + koff;

        const int wm = wave & 1, wn = wave >> 1;
        const int fr = lane & 15, kq = lane >> 4;
        const int kz = (kq ^ ((fr >> 1) & 3)) * 8;

        float p1 = 0.f, a1 = 0.f, p2 = 0.f, a2 = 0.f;

        for (int c = 0; c < 4; ++c) {
            const int t0 = c * 128;
            const int TCe = (TT - t0 < 128) ? (TT - t0) : 128;

            int r0 = rbl; if (r0 > TCe - 1) r0 = TCe - 1;
            const f16* gA0 = Xb + ((size_t)nA * TT + t0 + r0) * II + koff;

            auto stage = [&](int kk2, int bs) {
                f16* As_b = (f16*)(smem + bs * 24576);
                f16* Bh_b = As_b + 4096;
                f16* Bl_b = As_b + 8192;
                const int ko = kk2 * 32;
                gl2lds16(gA0 + ko, As_b + wave * 512);
                gl2lds16(gBh0 + ko, Bh_b + wave * 512);
                gl2lds16(gBl0 + ko, Bl_b + wave * 512);
            };
            stage(0, 0);
            stage(1, 1);

            f32x4 acc[4][2] = {};
#pragma unroll
            for (int kk = 0; kk < 8; ++kk) {
                if (kk < 7) asm volatile("s_waitcnt vmcnt(3)" ::: "memory");
                else        asm volatile("s_waitcnt vmcnt(0)" ::: "memory");
                __builtin_amdgcn_s_barrier();
                __builtin_amdgcn_sched_barrier(0);
                if (kk < 6) stage(kk + 2, (kk + 2) % 3);

                const f16* As_b = (const f16*)(smem + (kk % 3) * 24576);
                const f16* Bh_b = As_b + 4096;
                const f16* Bl_b = As_b + 8192;

                f16x8 av[4], bhv[2], blv[2];
#pragma unroll
                for (int i = 0; i < 4; ++i)
                    av[i] = *(const f16x8*)(As_b + (wm * 64 + i * 16 + fr) * 32 + kz);
#pragma unroll
                for (int j = 0; j < 2; ++j) {
                    bhv[j] = *(const f16x8*)(Bh_b + (wn * 32 + j * 16 + fr) * 32 + kz);
                    blv[j] = *(const f16x8*)(Bl_b + (wn * 32 + j * 16 + fr) * 32 + kz);
                }
                __builtin_amdgcn_s_setprio(1);
#pragma unroll
                for (int i = 0; i < 4; ++i)
#pragma unroll
                    for (int j = 0; j < 2; ++j) {
                        acc[i][j] = __builtin_amdgcn_mfma_f32_16x16x32_f16(av[i], bhv[j], acc[i][j], 0, 0, 0);
                        acc[i][j] = __builtin_amdgcn_mfma_f32_16x16x32_f16(av[i], blv[j], acc[i][j], 0, 0, 0);
                    }
                __builtin_amdgcn_s_setprio(0);
            }
            __syncthreads();

#pragma unroll
            for (int i = 0; i < 4; ++i)
#pragma unroll
                for (int j = 0; j < 2; ++j) {
                    int tr = wm * 64 + i * 16 + kq * 4;
                    int hc = wn * 32 + j * 16 + fr;
#pragma unroll
                    for (int r = 0; r < 4; ++r)
                        yb[(tr + r) * 132 + hc] = acc[i][j][r];
                }
            __syncthreads();

            if (tid < 128) {
                u64* sq = Sb + ((size_t)nA * TT + t0) * 16 + ht * 2 + wave;
                float rb_[8];
#pragma unroll
                for (int j = 0; j < 8; ++j) rb_[j] = yb[j * 132 + tid];
                int t = 0;
                for (; t + 8 <= TCe; t += 8) {
#pragma unroll
                    for (int j = 0; j < 8; ++j) {
                        float xv = rb_[j];
                        int tn = t + j + 8;
                        rb_[j] = (tn < TCe) ? yb[tn * 132 + tid] : 0.f;
                        a1 = D_SR * (a1 + p1);
                        p1 = D_SR * p1 + xv;
                        float ut = C_SR * a1;
                        a2 = D_RF * (a2 + p2);
                        float u = ut + C_RF * a2;
                        float s = (u >= THETA) ? 1.0f : 0.0f;
                        p2 = D_RF * p2 + REFS * s;
                        u64 m = __ballot(u >= THETA);
                        if (lane == 0) sq[(size_t)(t + j) * 16] = m;
                    }
                }
                int rem = TCe - t;
#pragma unroll
                for (int j = 0; j < 8; ++j) {
                    if (j < rem) {
                        float xv = rb_[j];
                        a1 = D_SR * (a1 + p1);
                        p1 = D_SR * p1 + xv;
                        float ut = C_SR * a1;
                        a2 = D_RF * (a2 + p2);
                        float u = ut + C_RF * a2;
                        float s = (u >= THETA) ? 1.0f : 0.0f;
                        p2 = D_RF * p2 + REFS * s;
                        u64 m = __ballot(u >= THETA);
                        if (lane == 0) sq[(size_t)(t + j) * 16] = m;
                    }
                }
            }
            __syncthreads();
        }

        // publish S1[nA] slice (8 producers per n)
        if (tid == 0) {
            __threadfence();
            __hip_atomic_fetch_add(done + nA, 1u, __ATOMIC_RELEASE, __HIP_MEMORY_SCOPE_AGENT);
        }
    }
    __syncthreads();

    // ================= PHASE B: gemm2 (R6-proven, waves 0-3) ================
    const int n0 = (b * 64) / 500, n1 = (b * 64 + 63) / 500;
    if (b < 500 && tid < 256) {
        while (__hip_atomic_load(done + n0, __ATOMIC_ACQUIRE, __HIP_MEMORY_SCOPE_AGENT) < 8u)
            __builtin_amdgcn_s_sleep(8);
        if (n1 != n0)
            while (__hip_atomic_load(done + n1, __ATOMIC_ACQUIRE, __HIP_MEMORY_SCOPE_AGENT) < 8u)
                __builtin_amdgcn_s_sleep(8);

        const uint* Ab = (const uint*)Sb;
        const int m0 = b * 64;
        const int fr = lane & 15, kq = lane >> 4;
        const int sh = kq * 8;
        const int srow = lane >> 2;
        const int koff = (((lane & 3) ^ ((lane >> 3) & 3))) * 8;
        const int kz = (kq ^ ((fr >> 1) & 3)) * 8;

        const f16* gh0 = W2h + (size_t)srow * HH + koff;
        const f16* gh1 = W2h + (size_t)(srow + 16) * HH + koff;
        const f16* gl0 = W2l + (size_t)srow * HH + koff;
        const f16* gl1 = W2l + (size_t)(srow + 16) * HH + koff;

        auto stage2 = [&](int kk2, int bs) {
            char* s = smem + (wave * 3 + bs) * 4096;
            const int ko = kk2 * 32;
            gl2lds16(gh0 + ko, s);
            gl2lds16(gh1 + ko, s + 1024);
            gl2lds16(gl0 + ko, s + 2048);
            gl2lds16(gl1 + ko, s + 3072);
        };

        const int row = m0 + wave * 16 + fr;
        const uint* arow = Ab + (size_t)row * 32;

        uint ac[1] = { arow[0] };
        uint an;
        stage2(0, 0);
        stage2(1, 1);

        f32x4 acc2[2] = {};
#pragma unroll
        for (int kk = 0; kk < 32; ++kk) {
            if (kk < 31) asm volatile("s_waitcnt vmcnt(4)" ::: "memory");
            else         asm volatile("s_waitcnt vmcnt(0)" ::: "memory");
            __builtin_amdgcn_sched_barrier(0);
            if (kk < 31) an = arow[kk + 1];
            if (kk < 30) stage2(kk + 2, (kk + 2) % 3);

            const f16* Bh_b = (const f16*)(smem + (wave * 3 + kk % 3) * 4096);
            const f16* Bl_b = Bh_b + 1024;

            const uint byte = (ac[0] >> sh) & 0xFFu;
            union { f16x8 v; uint u[4]; } A;
#pragma unroll
            for (int e = 0; e < 4; ++e) {
                uint b0 = (byte >> (2 * e)) & 1u, b1 = (byte >> (2 * e + 1)) & 1u;
                A.u[e] = (b0 ? 0x3C00u : 0u) | (b1 ? 0x3C000000u : 0u);
            }

            f16x8 bh[2], bl[2];
#pragma unroll
            for (int j = 0; j < 2; ++j) {
                bh[j] = *(const f16x8*)(Bh_b + (j * 16 + fr) * 32 + kz);
                bl[j] = *(const f16x8*)(Bl_b + (j * 16 + fr) * 32 + kz);
            }
#pragma unroll
            for (int j = 0; j < 2; ++j) {
                acc2[j] = __builtin_amdgcn_mfma_f32_16x16x32_f16(A.v, bh[j], acc2[j], 0, 0, 0);
                acc2[j] = __builtin_amdgcn_mfma_f32_16x16x32_f16(A.v, bl[j], acc2[j], 0, 0, 0);
            }
            ac[0] = an;
        }

#pragma unroll
        for (int j = 0; j < 2; ++j) {
            int rbase = m0 + wave * 16 + kq * 4;
            int cc = j * 16 + fr;
            float* p = Y2 + (size_t)rbase * 32 + cc;
#pragma unroll
            for (int r = 0; r < 4; ++r)
                p[(size_t)r * 32] = acc2[j][r];
        }
    }
    __syncthreads();
    if (b < 500 && tid == 0) {
        __threadfence();
        __hip_atomic_fetch_add(y2f + n0, 1u, __ATOMIC_RELEASE, __HIP_MEMORY_SCOPE_AGENT);
        if (n1 != n0)
            __hip_atomic_fetch_add(y2f + n1, 1u, __ATOMIC_RELEASE, __HIP_MEMORY_SCOPE_AGENT);
    }

    // ================= PHASE C: scan2 (blocks 0..63) ========================
    if (b < 64) {
        const int n = b;
        const uint expn = (uint)(((n + 1) * 500 - 1) / 64 - (n * 500) / 64 + 1);
        while (__hip_atomic_load(y2f + n, __ATOMIC_ACQUIRE, __HIP_MEMORY_SCOPE_AGENT) < expn)
            __builtin_amdgcn_s_sleep(8);
        __syncthreads();   // all threads saw flag; smem free for yc

        float* yc = (float*)smem;   // 64,000 B
        const float4* src = (const float4*)(Y2 + (size_t)n * TT * 32);
        float4* dst = (float4*)yc;
        for (int i = tid; i < TT * 8; i += 512) dst[i] = src[i];
        __syncthreads();

        if (tid < 32) {
            float p1 = 0.f, a1 = 0.f, p2 = 0.f, a2 = 0.f;
            float rb_[8];
            float* on = Out + (size_t)n * OO * TT + (size_t)tid * TT;
#pragma unroll
            for (int j = 0; j < 8; ++j) rb_[j] = yc[j * 32 + tid];
            int t = 0;
            for (; t + 8 <= TT; t += 8) {
#pragma unroll
                for (int j = 0; j < 8; ++j) {
                    float xv = rb_[j];
                    int tn = t + j + 8;
                    rb_[j] = (tn < TT) ? yc[tn * 32 + tid] : 0.f;
                    a1 = D_SR * (a1 + p1);
                    p1 = D_SR * p1 + xv;
                    float ut = C_SR * a1;
                    a2 = D_RF * (a2 + p2);
                    float u = ut + C_RF * a2;
                    float s = (u >= THETA) ? 1.0f : 0.0f;
                    p2 = D_RF * p2 + REFS * s;
                    if (tid < OO) on[t + j] = s;
                }
            }
#pragma unroll
            for (int j = 0; j < 8; ++j) {
                if (t + j < TT) {
                    float xv = rb_[j];
                    a1 = D_SR * (a1 + p1);
                    p1 = D_SR * p1 + xv;
                    float ut = C_SR * a1;
                    a2 = D_RF * (a2 + p2);
                    float u = ut + C_RF * a2;
                    float s = (u >= THETA) ? 1.0f : 0.0f;
                    p2 = D_RF * p2 + REFS * s;
                    if (tid < OO) on[t + j] = s;
                }
            }
        }
    }
}

extern "C" void kernel_launch(void* const* d_in, const int* in_sizes, int n_in,
                              void* d_out, int out_size, void* d_ws, size_t ws_size,
                              hipStream_t stream) {
    const float* X  = (const float*)d_in[0];
    const float* W1 = (const float*)d_in[1];
    const float* W2 = (const float*)d_in[2];
    float* out = (float*)d_out;

    const size_t s_sb = (size_t)NN * TT * 16 * 8;   //  4,096,000 (spike bits)
    const size_t s_Xb = (size_t)NN * TT * II * 2;   // 16,384,000
    const size_t s_W  = (size_t)HH * II * 2;        //    524,288 (x2)
    const size_t s_W2 = (size_t)32 * HH * 2;        //     65,536 (x2)
    const size_t s_y2 = (size_t)NN * TT * 32 * 4;   //  4,096,000

    char* w = (char*)d_ws;
    u64*   sbb = (u64*)w;  w += s_sb;
    f16*   Xb  = (f16*)w;  w += s_Xb;
    f16*   W1h = (f16*)w;  w += s_W;
    f16*   W1l = (f16*)w;  w += s_W;
    f16*   W2h = (f16*)w;  w += s_W2;
    f16*   W2l = (f16*)w;  w += s_W2;
    float* y2  = (float*)w; w += s_y2;
    uint*  flags = (uint*)w;                        // 128 u32, zeroed by prep

    prep_all<<<3200, 256, 0, stream>>>(X, W1, W2, Xb, W1h, W1l, W2h, W2l, flags);

    mega<<<512, 512, 0, stream>>>(Xb, W1h, W1l, sbb, W2h, W2l, y2, out, flags);
}

// Round 10
// 188.998 us; speedup vs baseline: 1.4843x; 1.4843x over previous
//
#include <hip/hip_runtime.h>

// SNN forward (best-known R4 config + vectorized prep): [prep v2: float4
// reads, f16x8 stores, 328 blocks] -> [GEMM1+scan1 fused, 128x128, ring-3
// LDS counted-vmcnt K-loop, 512 thr / 8 waves] -> GEMM2 (64-row, ring-5
// depth-4) -> scan2 (single-phase LDS, static ring).
// f16 split-2: W = hi + lo (both f16), residual ~2^-24 => fp32-grade MFMA.
// R10 ledger: gemm1 66.5 invariant across 6 structures (conflicts-0, vmcnt
// depth, staging width, bit-A(83, VALU tax), interleave(81, occupancy),
// mega-fusion(208, XCD-fence tax)). rest 120-122 interior-invariant; volume
// models leave ~80us unattributed. prep is the ONLY never-probed kernel and
// violates G13 (scalar f32 loads, 2B f16 stores) -> this round = clean A/B
// on prep alone; everything else byte-identical to R4 (187.65).

#define NN 64
#define II 256
#define HH 1024
#define OO 18
#define TT 500

#define D_SR 0.9048374180359595f   // exp(-1/10)
#define C_SR 0.27182818284590454f  // e/10
#define D_RF 0.36787944117144233f  // exp(-1)
#define C_RF 2.718281828459045f    // e
#define THETA 10.0f
#define REFS (-20.0f)

typedef _Float16 f16;
typedef _Float16 f16x8 __attribute__((ext_vector_type(8)));
typedef _Float16 f16x4 __attribute__((ext_vector_type(4)));
typedef float f32x4 __attribute__((ext_vector_type(4)));

__device__ __forceinline__ void gl2lds16(const void* g, void* l) {
    __builtin_amdgcn_global_load_lds(
        (const __attribute__((address_space(1))) void*)g,
        (__attribute__((address_space(3))) void*)l, 16, 0, 0);
}

// ---------------- prep v2: vectorized X transpose + W1/W2 hi-lo splits ------
// grid 328: [0,256) X tiles (n x i-quarter, 8 t-tiles each, float4 reads,
// f16x8 stores), [256,320) W1 (float4), [320,328) W2 (float4).
__launch_bounds__(256)
__global__ void prep_all(const float* __restrict__ X, const float* __restrict__ W1,
                         const float* __restrict__ W2, f16* __restrict__ Xb,
                         f16* __restrict__ W1h, f16* __restrict__ W1l,
                         f16* __restrict__ W2h, f16* __restrict__ W2l) {
    const int b = blockIdx.x;
    const int tid = threadIdx.x;

    if (b < 256) {
        __shared__ float tile[64][65];
        const int n = b >> 2, i0 = (b & 3) * 64;
        const float* Xn = X + (size_t)n * II * TT;
        f16* Xo = Xb + (size_t)n * TT * II + i0;

        const int q = tid >> 4, s = tid & 15;      // load role
        const int io = (tid & 7) * 8, tl = tid >> 3;  // store role

        for (int tt = 0; tt < 8; ++tt) {
            const int t0 = tt * 64;
            const int tw = (TT - t0 < 64) ? (TT - t0) : 64;   // 64 or 52

            __syncthreads();   // previous tile's readers done
            // load: rows il = p*16+q, float4 at t = t0 + s*4 (500 = 4*125:
            // reads never straddle; tail tile is exactly 13 full float4s)
#pragma unroll
            for (int p = 0; p < 4; ++p) {
                int il = p * 16 + q;
                int t = t0 + s * 4;
                float4 v = make_float4(0.f, 0.f, 0.f, 0.f);
                if (t < TT) v = *(const float4*)(Xn + (size_t)(i0 + il) * TT + t);
                tile[il][s * 4 + 0] = v.x;
                tile[il][s * 4 + 1] = v.y;
                tile[il][s * 4 + 2] = v.z;
                tile[il][s * 4 + 3] = v.w;
            }
            __syncthreads();
            // store: lane packs 8 i into one 16B f16x8 per t
#pragma unroll
            for (int r = 0; r < 2; ++r) {
                int t = r * 32 + tl;
                if (t < tw) {
                    f16x8 vv;
#pragma unroll
                    for (int e = 0; e < 8; ++e) vv[e] = (f16)tile[io + e][t];
                    *(f16x8*)(Xo + (size_t)(t0 + t) * II + io) = vv;
                }
            }
        }
    } else if (b < 320) {
        size_t i4 = ((size_t)(b - 256) * 256 + tid) * 4;
        float4 w = *(const float4*)(W1 + i4);
        f16x4 h, l;
        h[0] = (f16)w.x; l[0] = (f16)(w.x - (float)h[0]);
        h[1] = (f16)w.y; l[1] = (f16)(w.y - (float)h[1]);
        h[2] = (f16)w.z; l[2] = (f16)(w.z - (float)h[2]);
        h[3] = (f16)w.w; l[3] = (f16)(w.w - (float)h[3]);
        *(f16x4*)(W1h + i4) = h;
        *(f16x4*)(W1l + i4) = l;
    } else {
        size_t i4 = ((size_t)(b - 320) * 256 + tid) * 4;
        int o = (int)(i4 >> 10);   // uniform across the aligned float4
        float4 w = (o < OO) ? *(const float4*)(W2 + i4)
                            : make_float4(0.f, 0.f, 0.f, 0.f);
        f16x4 h, l;
        h[0] = (f16)w.x; l[0] = (f16)(w.x - (float)h[0]);
        h[1] = (f16)w.y; l[1] = (f16)(w.y - (float)h[1]);
        h[2] = (f16)w.z; l[2] = (f16)(w.z - (float)h[2]);
        h[3] = (f16)w.w; l[3] = (f16)(w.w - (float)h[3]);
        *(f16x4*)(W2h + i4) = h;
        *(f16x4*)(W2l + i4) = l;
    }
}

// ---------------- FUSED layer 1: 128x128 tile, ring-3 K-loop, 8 waves ------
// grid (8, 64), 512 thr. Per block: 4 t-chunks of 128.
// Wave layout 2m x 4n. Staging: wave w stages rows [w*16, w*16+16).
// LDS swizzle: physical 16B slot p of row r holds logical slot p ^ ((r>>1)&3)
// => applied to SOURCE k-offset at stage, and to read addr. 2-way max (free).
__launch_bounds__(512)
__global__ void gemm1_scan1(const f16* __restrict__ Xb, const f16* __restrict__ Wh,
                            const f16* __restrict__ Wl, f16* __restrict__ S1) {
    __shared__ __align__(16) char smem[3 * 24576];  // 73,728 B (yb uses 67,584)
    float* yb = (float*)smem;

    const int tid = threadIdx.x;
    const int wave = tid >> 6, lane = tid & 63;

    // XCD swizzle: the 8 h-tiles of one n share an XCD
    const int f = blockIdx.y * 8 + blockIdx.x;
    const int x = f & 7, g = f >> 3;
    const int n = x * 8 + (g & 7);
    const int ht = g >> 3;
    const int h0g = ht * 128;

    const int rbl = wave * 16 + (lane >> 2);   // staged row 0..127
    // swizzled source slot: (lane&3) ^ sigma(row), sigma(row)=(lane>>3)&3
    const int koff = (((lane & 3) ^ ((lane >> 3) & 3))) * 8;
    const f16* gBh0 = Wh + (size_t)(h0g + rbl) * II + koff;
    const f16* gBl0 = Wl + (size_t)(h0g + rbl) * II + koff;

    const int wm = wave & 1, wn = wave >> 1;   // 2m x 4n
    const int fr = lane & 15, kq = lane >> 4;
    const int kz = (kq ^ ((fr >> 1) & 3)) * 8;  // swizzled read slot (f16 idx)

    float p1 = 0.f, a1 = 0.f, p2 = 0.f, a2 = 0.f;  // scan state (tid<128)

    for (int c = 0; c < 4; ++c) {
        const int t0 = c * 128;
        const int TCe = (TT - t0 < 128) ? (TT - t0) : 128;

        int r0 = rbl; if (r0 > TCe - 1) r0 = TCe - 1;
        const f16* gA0 = Xb + ((size_t)n * TT + t0 + r0) * II + koff;

        auto stage = [&](int kk2, int b) {
            f16* As_b = (f16*)(smem + b * 24576);
            f16* Bh_b = As_b + 4096;   // f16 elements: As = 128*32 = 4096
            f16* Bl_b = As_b + 8192;
            const int ko = kk2 * 32;
            gl2lds16(gA0 + ko, As_b + wave * 512);
            gl2lds16(gBh0 + ko, Bh_b + wave * 512);
            gl2lds16(gBl0 + ko, Bl_b + wave * 512);
        };

        // prologue: prev chunk's post-scan barrier protects buf0/buf1 (yb)
        stage(0, 0);
        stage(1, 1);

        f32x4 acc[4][2] = {};
#pragma unroll
        for (int kk = 0; kk < 8; ++kk) {
            // buf[kk%3] DMA done when only the newest stage (3 loads) is
            // outstanding; vmcnt retires in order (m135).
            if (kk < 7) asm volatile("s_waitcnt vmcnt(3)" ::: "memory");
            else        asm volatile("s_waitcnt vmcnt(0)" ::: "memory");
            __builtin_amdgcn_s_barrier();
            __builtin_amdgcn_sched_barrier(0);
            if (kk < 6) stage(kk + 2, (kk + 2) % 3);

            const f16* As_b = (const f16*)(smem + (kk % 3) * 24576);
            const f16* Bh_b = As_b + 4096;
            const f16* Bl_b = As_b + 8192;

            f16x8 av[4], bhv[2], blv[2];
#pragma unroll
            for (int i = 0; i < 4; ++i)
                av[i] = *(const f16x8*)(As_b + (wm * 64 + i * 16 + fr) * 32 + kz);
#pragma unroll
            for (int j = 0; j < 2; ++j) {
                bhv[j] = *(const f16x8*)(Bh_b + (wn * 32 + j * 16 + fr) * 32 + kz);
                blv[j] = *(const f16x8*)(Bl_b + (wn * 32 + j * 16 + fr) * 32 + kz);
            }
            __builtin_amdgcn_s_setprio(1);
#pragma unroll
            for (int i = 0; i < 4; ++i)
#pragma unroll
                for (int j = 0; j < 2; ++j) {
                    acc[i][j] = __builtin_amdgcn_mfma_f32_16x16x32_f16(av[i], bhv[j], acc[i][j], 0, 0, 0);
                    acc[i][j] = __builtin_amdgcn_mfma_f32_16x16x32_f16(av[i], blv[j], acc[i][j], 0, 0, 0);
                }
            __builtin_amdgcn_s_setprio(0);
        }
        __syncthreads();  // all frag reads done before epilogue overwrites staging

        // epilogue: acc -> yb (t-major, stride 132)
#pragma unroll
        for (int i = 0; i < 4; ++i)
#pragma unroll
            for (int j = 0; j < 2; ++j) {
                int tr = wm * 64 + i * 16 + kq * 4;
                int hc = wn * 32 + j * 16 + fr;
#pragma unroll
                for (int r = 0; r < 4; ++r)
                    yb[(tr + r) * 132 + hc] = acc[i][j][r];
            }
        __syncthreads();

        // sequential scan (waves 0-1); 8-deep ring; spikes -> global directly
        if (tid < 128) {
            f16* sq = S1 + ((size_t)n * TT + t0) * HH + h0g + tid;
            float rb_[8];
#pragma unroll
            for (int j = 0; j < 8; ++j) rb_[j] = yb[j * 132 + tid];
            int t = 0;
            for (; t + 8 <= TCe; t += 8) {
#pragma unroll
                for (int j = 0; j < 8; ++j) {
                    float xv = rb_[j];
                    int tn = t + j + 8;
                    rb_[j] = (tn < TCe) ? yb[tn * 132 + tid] : 0.f;
                    a1 = D_SR * (a1 + p1);
                    p1 = D_SR * p1 + xv;
                    float ut = C_SR * a1;
                    a2 = D_RF * (a2 + p2);
                    float u = ut + C_RF * a2;
                    float s = (u >= THETA) ? 1.0f : 0.0f;
                    p2 = D_RF * p2 + REFS * s;
                    sq[(size_t)(t + j) * HH] = (f16)s;
                }
            }
            int rem = TCe - t;
#pragma unroll
            for (int j = 0; j < 8; ++j) {
                if (j < rem) {
                    float xv = rb_[j];
                    a1 = D_SR * (a1 + p1);
                    p1 = D_SR * p1 + xv;
                    float ut = C_SR * a1;
                    a2 = D_RF * (a2 + p2);
                    float u = ut + C_RF * a2;
                    float s = (u >= THETA) ? 1.0f : 0.0f;
                    p2 = D_RF * p2 + REFS * s;
                    sq[(size_t)(t + j) * HH] = (f16)s;
                }
            }
        }
        __syncthreads();  // yb reads done; next chunk's staging may overwrite
    }
}

// ---------------- GEMM2 (MFMA, split-f16, ring-5 depth-4, 64-row tiles) -----
// grid 500; 256 thr; tile 64 m x 32 o; K=1024, BK=32.
__launch_bounds__(256)
__global__ void gemm2_mfma(const f16* __restrict__ S1, const f16* __restrict__ W2h,
                           const f16* __restrict__ W2l, float* __restrict__ Y2) {
    __shared__ __align__(16) f16 As[5][64 * 32];  // 5 x 4 KB
    __shared__ __align__(16) f16 Bh[5][32 * 32];  // 5 x 2 KB
    __shared__ __align__(16) f16 Bl[5][32 * 32];  // 5 x 2 KB

    const int tid = threadIdx.x;
    const int wave = tid >> 6, lane = tid & 63;
    const int m0 = blockIdx.x * 64;
    const int fr = lane & 15, kq = lane >> 4;
    const int koff = (((lane & 3) ^ ((lane >> 3) & 3))) * 8;  // swizzled src slot
    const int kz = (kq ^ ((fr >> 1) & 3)) * 8;                // swizzled read slot

    const f16* gA = S1 + (size_t)(m0 + wave * 16 + (lane >> 2)) * HH + koff;
    const f16* gB = (wave < 2 ? W2h : W2l) + (size_t)((wave & 1) * 16 + (lane >> 2)) * HH + koff;

    auto stage = [&](int kk2, int b) {
        const int ko = kk2 * 32;
        gl2lds16(gA + ko, &As[b][wave * 512]);
        gl2lds16(gB + ko, (wave < 2 ? &Bh[b][0] : &Bl[b][0]) + (wave & 1) * 512);
    };

    stage(0, 0);
    stage(1, 1);
    stage(2, 2);
    stage(3, 3);

    f32x4 acc[2] = {};
#pragma unroll
    for (int kk = 0; kk < HH / 32; ++kk) {
        // steady: 3 newer stages (6 loads) may stay in flight; tail drains.
        if (kk <= HH / 32 - 4)      asm volatile("s_waitcnt vmcnt(6)" ::: "memory");
        else if (kk == HH / 32 - 3) asm volatile("s_waitcnt vmcnt(4)" ::: "memory");
        else if (kk == HH / 32 - 2) asm volatile("s_waitcnt vmcnt(2)" ::: "memory");
        else                        asm volatile("s_waitcnt vmcnt(0)" ::: "memory");
        __builtin_amdgcn_s_barrier();
        __builtin_amdgcn_sched_barrier(0);
        if (kk < HH / 32 - 4) stage(kk + 4, (kk + 4) % 5);
        const int b = kk % 5;

        f16x8 a, bh[2], bl[2];
        a = *(const f16x8*)(&As[b][(wave * 16 + fr) * 32 + kz]);
#pragma unroll
        for (int j = 0; j < 2; ++j) {
            bh[j] = *(const f16x8*)(&Bh[b][(j * 16 + fr) * 32 + kz]);
            bl[j] = *(const f16x8*)(&Bl[b][(j * 16 + fr) * 32 + kz]);
        }
        __builtin_amdgcn_s_setprio(1);
#pragma unroll
        for (int j = 0; j < 2; ++j) {
            acc[j] = __builtin_amdgcn_mfma_f32_16x16x32_f16(a, bh[j], acc[j], 0, 0, 0);
            acc[j] = __builtin_amdgcn_mfma_f32_16x16x32_f16(a, bl[j], acc[j], 0, 0, 0);
        }
        __builtin_amdgcn_s_setprio(0);
    }

#pragma unroll
    for (int j = 0; j < 2; ++j) {
        int rbase = m0 + wave * 16 + kq * 4;
        int cc = j * 16 + fr;
        float* p = Y2 + (size_t)rbase * 32 + cc;
#pragma unroll
        for (int r = 0; r < 4; ++r)
            p[(size_t)r * 32] = acc[j][r];
    }
}

// ---------------- scan2: single-phase LDS, static-index ring ----------------
__launch_bounds__(256)
__global__ void scan2_k(const float* __restrict__ Y2, float* __restrict__ Out) {
    __shared__ float yc[TT * 32];    // 64,000 B
    __shared__ float sb[OO * TT];    // 36,000 B
    const int n = blockIdx.x, tid = threadIdx.x;

    const float4* src = (const float4*)(Y2 + (size_t)n * TT * 32);
    float4* dst = (float4*)yc;
    for (int i = tid; i < TT * 8; i += 256) dst[i] = src[i];
    __syncthreads();

    if (tid < 32) {
        float p1 = 0.f, a1 = 0.f, p2 = 0.f, a2 = 0.f;
        float rb_[8];
#pragma unroll
        for (int j = 0; j < 8; ++j) rb_[j] = yc[j * 32 + tid];
        int t = 0;
        for (; t + 8 <= TT; t += 8) {
#pragma unroll
            for (int j = 0; j < 8; ++j) {
                float xv = rb_[j];
                int tn = t + j + 8;
                rb_[j] = (tn < TT) ? yc[tn * 32 + tid] : 0.f;
                a1 = D_SR * (a1 + p1);
                p1 = D_SR * p1 + xv;
                float ut = C_SR * a1;
                a2 = D_RF * (a2 + p2);
                float u = ut + C_RF * a2;
                float s = (u >= THETA) ? 1.0f : 0.0f;
                p2 = D_RF * p2 + REFS * s;
                if (tid < OO) sb[tid * TT + t + j] = s;
            }
        }
#pragma unroll
        for (int j = 0; j < 8; ++j) {
            if (t + j < TT) {
                float xv = rb_[j];
                a1 = D_SR * (a1 + p1);
                p1 = D_SR * p1 + xv;
                float ut = C_SR * a1;
                a2 = D_RF * (a2 + p2);
                float u = ut + C_RF * a2;
                float s = (u >= THETA) ? 1.0f : 0.0f;
                p2 = D_RF * p2 + REFS * s;
                if (tid < OO) sb[tid * TT + t + j] = s;
            }
        }
    }
    __syncthreads();

    float* on = Out + (size_t)n * OO * TT;
    for (int e = tid; e < OO * TT; e += 256) on[e] = sb[e];
}

extern "C" void kernel_launch(void* const* d_in, const int* in_sizes, int n_in,
                              void* d_out, int out_size, void* d_ws, size_t ws_size,
                              hipStream_t stream) {
    const float* X  = (const float*)d_in[0];
    const float* W1 = (const float*)d_in[1];
    const float* W2 = (const float*)d_in[2];
    float* out = (float*)d_out;

    const size_t s_s1 = (size_t)NN * TT * HH * 2;   // 65,536,000
    const size_t s_Xb = (size_t)NN * TT * II * 2;   // 16,384,000
    const size_t s_W  = (size_t)HH * II * 2;        //    524,288 (x2)
    const size_t s_W2 = (size_t)32 * HH * 2;        //     65,536 (x2)
    // + y2 4,096,000 => ~87 MB total

    char* w = (char*)d_ws;
    f16*   s1b = (f16*)w;  w += s_s1;
    f16*   Xb  = (f16*)w;  w += s_Xb;
    f16*   W1h = (f16*)w;  w += s_W;
    f16*   W1l = (f16*)w;  w += s_W;
    f16*   W2h = (f16*)w;  w += s_W2;
    f16*   W2l = (f16*)w;  w += s_W2;
    float* y2  = (float*)w;

    prep_all<<<328, 256, 0, stream>>>(X, W1, W2, Xb, W1h, W1l, W2h, W2l);

    gemm1_scan1<<<dim3(8, NN), 512, 0, stream>>>(Xb, W1h, W1l, s1b);

    gemm2_mfma<<<(NN * TT) / 64, 256, 0, stream>>>(s1b, W2h, W2l, y2);
    scan2_k<<<NN, 256, 0, stream>>>(y2, out);
}